// Round 8
// baseline (389.792 us; speedup 1.0000x reference)
//
#include <hip/hip_runtime.h>
#include <math.h>

#define N_NODES_C 100000
#define N_EDGES_C 1600000
#define IN_DIM_C 64
#define HID_C 128
#define N_ASSETS_C 50
#define N_GRAPHS_C 64

#define BKT_SHIFT 9
#define BKT_NODES 512
#define NB_BKT ((N_NODES_C + BKT_NODES - 1) / BKT_NODES)   // 196
#define EPB_A 8192
#define NBLK_A ((N_EDGES_C + EPB_A - 1) / EPB_A)            // 196

typedef __attribute__((ext_vector_type(8))) short bf16x8;
typedef __attribute__((ext_vector_type(4))) float f32x4;

__device__ __forceinline__ unsigned short f2bf(float f) {
    unsigned u = __float_as_uint(f);
    return (unsigned short)((u + 0x7FFFu + ((u >> 16) & 1u)) >> 16);
}
__device__ __forceinline__ float bf2f(unsigned short b) {
    return __uint_as_float((unsigned)b << 16);
}
__device__ __forceinline__ void acc_bf8(float* acc, uint4 v) {
    acc[0] += __uint_as_float(v.x << 16);
    acc[1] += __uint_as_float(v.x & 0xFFFF0000u);
    acc[2] += __uint_as_float(v.y << 16);
    acc[3] += __uint_as_float(v.y & 0xFFFF0000u);
    acc[4] += __uint_as_float(v.z << 16);
    acc[5] += __uint_as_float(v.z & 0xFFFF0000u);
    acc[6] += __uint_as_float(v.w << 16);
    acc[7] += __uint_as_float(v.w & 0xFFFF0000u);
}
__device__ __forceinline__ uint4 pack_bf8(const float* acc) {
    uint4 o;
    o.x = (unsigned)f2bf(acc[0]) | ((unsigned)f2bf(acc[1]) << 16);
    o.y = (unsigned)f2bf(acc[2]) | ((unsigned)f2bf(acc[3]) << 16);
    o.z = (unsigned)f2bf(acc[4]) | ((unsigned)f2bf(acc[5]) << 16);
    o.w = (unsigned)f2bf(acc[6]) | ((unsigned)f2bf(acc[7]) << 16);
    return o;
}

// ---------------------------------------------------------------------------
// fp32 -> bf16 cast (vectorized), n4 = count/4
// ---------------------------------------------------------------------------
__global__ __launch_bounds__(256) void cast_bf16_kernel(
    const float* __restrict__ src, unsigned short* __restrict__ dst, int n4)
{
    int i = blockIdx.x * 256 + threadIdx.x;
    if (i < n4) {
        float4 v = ((const float4*)src)[i];
        ushort4 o;
        o.x = f2bf(v.x); o.y = f2bf(v.y); o.z = f2bf(v.z); o.w = f2bf(v.w);
        ((ushort4*)dst)[i] = o;
    }
}

// ---------------------------------------------------------------------------
// Pack all 4 fp32 weights into MFMA B-fragments (split hi/lo bf16), 1 launch.
// blocks 0..15: w1_rel, 16..31: w1_root, 32..63: w2_rel, 64..95: w2_root.
// ---------------------------------------------------------------------------
__device__ __forceinline__ void pack_w_body(
    const float* __restrict__ W, unsigned short* __restrict__ dst, int bid, int lane)
{
    int kc = bid >> 3;
    int ct = bid & 7;
    int quad = lane >> 4;
    int l16 = lane & 15;
    unsigned short hi[8], lo[8];
#pragma unroll
    for (int j = 0; j < 8; ++j) {
        float w = W[(size_t)(kc * 32 + quad * 8 + j) * HID_C + ct * 16 + l16];
        unsigned short h = f2bf(w);
        float r = w - bf2f(h);
        hi[j] = h;
        lo[j] = f2bf(r);
    }
    size_t base = ((size_t)(kc * 8 + ct) * 2) * 512 + (size_t)lane * 8;
#pragma unroll
    for (int j = 0; j < 8; ++j) {
        dst[base + j] = hi[j];
        dst[base + 512 + j] = lo[j];
    }
}

__global__ __launch_bounds__(64) void pack_all_kernel(
    const float* __restrict__ w1r, const float* __restrict__ w1o,
    const float* __restrict__ w2r, const float* __restrict__ w2o,
    unsigned short* __restrict__ p1r, unsigned short* __restrict__ p1o,
    unsigned short* __restrict__ p2r, unsigned short* __restrict__ p2o)
{
    int b = blockIdx.x;
    int lane = threadIdx.x;
    if (b < 16)       pack_w_body(w1r, p1r, b, lane);
    else if (b < 32)  pack_w_body(w1o, p1o, b - 16, lane);
    else if (b < 64)  pack_w_body(w2r, p2r, b - 32, lane);
    else              pack_w_body(w2o, p2o, b - 64, lane);
}

// ---------------------------------------------------------------------------
// CSR build: bucketed counting sort.
// ---------------------------------------------------------------------------
__global__ __launch_bounds__(256) void bucket_hist_kernel(
    const int* __restrict__ ei, int* __restrict__ bcnt)
{
    __shared__ int cnt[NB_BKT];
    int t = threadIdx.x;
    for (int i = t; i < NB_BKT; i += 256) cnt[i] = 0;
    __syncthreads();
    int base = blockIdx.x * 2048;
#pragma unroll
    for (int i = 0; i < 8; ++i) {
        int e = base + i * 256 + t;
        if (e < N_EDGES_C) {
            int dst = ei[N_EDGES_C + e];
            atomicAdd(&cnt[dst >> BKT_SHIFT], 1);
        }
    }
    __syncthreads();
    for (int i = t; i < NB_BKT; i += 256)
        if (cnt[i]) atomicAdd(&bcnt[i], cnt[i]);
}

__global__ __launch_bounds__(256) void bucket_scan_kernel(
    const int* __restrict__ bcnt, int* __restrict__ bbase, int* __restrict__ gcur)
{
    __shared__ int s[256];
    int t = threadIdx.x;
    int v = (t < NB_BKT) ? bcnt[t] : 0;
    s[t] = v;
    __syncthreads();
    for (int o = 1; o < 256; o <<= 1) {
        int x = (t >= o) ? s[t - o] : 0;
        __syncthreads();
        s[t] += x;
        __syncthreads();
    }
    int excl = s[t] - v;
    if (t < NB_BKT) { bbase[t] = excl; gcur[t] = excl; }
    if (t == 255) bbase[NB_BKT] = s[255];
}

__global__ __launch_bounds__(256) void partition_kernel(
    const int* __restrict__ ei, int* __restrict__ gcur,
    unsigned* __restrict__ tmp)
{
    __shared__ unsigned stage[EPB_A];
    __shared__ unsigned stage2[EPB_A];
    __shared__ unsigned char sbkt[EPB_A];
    __shared__ unsigned char sbkt2[EPB_A];
    __shared__ int cnt[NB_BKT];
    __shared__ int base[NB_BKT];
    __shared__ int cur[NB_BKT];
    __shared__ int gb[NB_BKT];
    __shared__ int s[256];

    const int t = threadIdx.x;
    const int e0 = blockIdx.x * EPB_A;
    const int nE = min(EPB_A, N_EDGES_C - e0);

    for (int i = t; i < NB_BKT; i += 256) cnt[i] = 0;
    __syncthreads();

    for (int idx = t; idx < nE; idx += 256) {
        int e = e0 + idx;
        int src = ei[e];
        int dst = ei[N_EDGES_C + e];
        int b = dst >> BKT_SHIFT;
        stage[idx] = ((unsigned)(dst & (BKT_NODES - 1)) << 17) | (unsigned)src;
        sbkt[idx] = (unsigned char)b;
        atomicAdd(&cnt[b], 1);
    }
    __syncthreads();

    int v = (t < NB_BKT) ? cnt[t] : 0;
    s[t] = v;
    __syncthreads();
    for (int o = 1; o < 256; o <<= 1) {
        int x = (t >= o) ? s[t - o] : 0;
        __syncthreads();
        s[t] += x;
        __syncthreads();
    }
    if (t < NB_BKT) {
        int excl = s[t] - v;
        base[t] = excl;
        cur[t] = excl;
        gb[t] = atomicAdd(&gcur[t], v);
    }
    __syncthreads();

    for (int idx = t; idx < nE; idx += 256) {
        int b = sbkt[idx];
        int p = atomicAdd(&cur[b], 1);
        stage2[p] = stage[idx];
        sbkt2[p] = (unsigned char)b;
    }
    __syncthreads();

    for (int idx = t; idx < nE; idx += 256) {
        int b = sbkt2[idx];
        int dest = gb[b] + (idx - base[b]);
        tmp[dest] = stage2[idx];
    }
}

__global__ __launch_bounds__(256) void bucket_sort_kernel(
    const unsigned* __restrict__ tmp, const int* __restrict__ bbase,
    int* __restrict__ row_ptr, int* __restrict__ col)
{
    __shared__ int ldeg[BKT_NODES];
    __shared__ int lsum[256];
    const int t = threadIdx.x;
    const int b = blockIdx.x;
    const int beg = bbase[b];
    const int end = bbase[b + 1];

    ldeg[t] = 0; ldeg[t + 256] = 0;
    __syncthreads();

    for (int p = beg + t; p < end; p += 256)
        atomicAdd(&ldeg[tmp[p] >> 17], 1);
    __syncthreads();

    int a0 = ldeg[2 * t], a1 = ldeg[2 * t + 1];
    int pair = a0 + a1;
    lsum[t] = pair;
    __syncthreads();
    for (int o = 1; o < 256; o <<= 1) {
        int x = (t >= o) ? lsum[t - o] : 0;
        __syncthreads();
        lsum[t] += x;
        __syncthreads();
    }
    int ep = lsum[t] - pair;
    __syncthreads();
    ldeg[2 * t] = ep;
    ldeg[2 * t + 1] = ep + a0;

    int gn0 = b * BKT_NODES + 2 * t;
    if (gn0 < N_NODES_C)     row_ptr[gn0] = beg + ep;
    if (gn0 + 1 < N_NODES_C) row_ptr[gn0 + 1] = beg + ep + a0;
    if (b == NB_BKT - 1 && t == 0) row_ptr[N_NODES_C] = N_EDGES_C;
    __syncthreads();

    for (int p = beg + t; p < end; p += 256) {
        unsigned v = tmp[p];
        int pos = atomicAdd(&ldeg[v >> 17], 1);
        col[beg + pos] = (int)(v & 0x1FFFFu);
    }
}

// ---------------------------------------------------------------------------
// MFMA conv phases: A from LDS tile (padded rows), X from global.
// ---------------------------------------------------------------------------
template<int K>
__device__ __forceinline__ void conv_phase_g(
    const unsigned short* __restrict__ P, const unsigned short* __restrict__ WP,
    const int* rowIdx, int quad, int lane, int wv, f32x4 acc[4][2])
{
#pragma unroll
    for (int kc = 0; kc < K / 32; ++kc) {
        bf16x8 afr[4];
#pragma unroll
        for (int rt = 0; rt < 4; ++rt)
            afr[rt] = *(const bf16x8*)(P + (size_t)rowIdx[rt] * K + kc * 32 + quad * 8);
#pragma unroll
        for (int ci = 0; ci < 2; ++ci) {
            int ct = wv * 2 + ci;
            const unsigned short* bp = WP + ((size_t)(kc * 8 + ct) * 2) * 512 + (size_t)lane * 8;
            bf16x8 bhi = *(const bf16x8*)bp;
            bf16x8 blo = *(const bf16x8*)(bp + 512);
#pragma unroll
            for (int rt = 0; rt < 4; ++rt) {
                acc[rt][ci] = __builtin_amdgcn_mfma_f32_16x16x32_bf16(afr[rt], bhi, acc[rt][ci], 0, 0, 0);
                acc[rt][ci] = __builtin_amdgcn_mfma_f32_16x16x32_bf16(afr[rt], blo, acc[rt][ci], 0, 0, 0);
            }
        }
    }
}

template<int K, int RS>
__device__ __forceinline__ void conv_phase_lds(
    const unsigned short* __restrict__ sA, const unsigned short* __restrict__ WP,
    int quad, int lane, int wv, int l16, f32x4 acc[4][2])
{
#pragma unroll
    for (int kc = 0; kc < K / 32; ++kc) {
        bf16x8 afr[4];
#pragma unroll
        for (int rt = 0; rt < 4; ++rt)
            afr[rt] = *(const bf16x8*)(sA + (size_t)(rt * 16 + l16) * RS + kc * 32 + quad * 8);
#pragma unroll
        for (int ci = 0; ci < 2; ++ci) {
            int ct = wv * 2 + ci;
            const unsigned short* bp = WP + ((size_t)(kc * 8 + ct) * 2) * 512 + (size_t)lane * 8;
            bf16x8 bhi = *(const bf16x8*)bp;
            bf16x8 blo = *(const bf16x8*)(bp + 512);
#pragma unroll
            for (int rt = 0; rt < 4; ++rt) {
                acc[rt][ci] = __builtin_amdgcn_mfma_f32_16x16x32_bf16(afr[rt], bhi, acc[rt][ci], 0, 0, 0);
                acc[rt][ci] = __builtin_amdgcn_mfma_f32_16x16x32_bf16(afr[rt], blo, acc[rt][ci], 0, 0, 0);
            }
        }
    }
}

// ---------------------------------------------------------------------------
// Fused gather+conv: per block of 64 nodes,
//   phase 1: gather neighbor sums (bf16 rows, K wide) into LDS tile,
//   phase 2: out = relu([aggLDS|X] @ [Wr;Wo] + bias)  (+ optional fused pool).
// Gather: wave wv owns nodes wv*16..wv*16+15 sequentially; SG=K/8 lanes per
// subgroup cover one 16B row chunk; NSG subgroups take NSG edges in flight.
// ---------------------------------------------------------------------------
template<int K, bool POOL>
__global__ __launch_bounds__(256) void fused_conv_kernel(
    const unsigned short* __restrict__ feat, const unsigned short* __restrict__ X,
    const int* __restrict__ row_ptr, const int* __restrict__ col,
    const unsigned short* __restrict__ WrP, const unsigned short* __restrict__ WoP,
    const float* __restrict__ bias, const int* __restrict__ batch,
    float* __restrict__ pooled, unsigned short* __restrict__ outp, int N)
{
    constexpr int RS = K + 8;            // padded LDS row stride (shorts)
    constexpr int SG = K / 8;            // lanes per row-chunk group (16B each)
    constexpr int NSG = 64 / SG;         // edge subgroups per wave
    __shared__ __align__(16) unsigned short sA[64 * RS];
    __shared__ int sbatch[64];

    const int t = threadIdx.x;
    const int wv = t >> 6;
    const int lane = t & 63;
    const int quad = lane >> 4;
    const int l16 = lane & 15;
    const int n0 = blockIdx.x * 64;

    if (POOL && t < 64) {
        int node = n0 + t;
        sbatch[t] = (node < N) ? batch[node] : -1;
    }

    // ---- phase 1: gather into LDS ----
    {
        const int sg = lane / SG;
        const int c  = lane % SG;
        const uint4* f4 = (const uint4*)feat;
        for (int i = 0; i < 16; ++i) {
            int ln = wv * 16 + i;
            int n = n0 + ln;
            int beg = 0, end = 0;
            if (n < N) { beg = row_ptr[n]; end = row_ptr[n + 1]; }
            float acc[8];
#pragma unroll
            for (int j = 0; j < 8; ++j) acc[j] = 0.f;
            int e = beg + sg;
            for (; e + NSG < end; e += 2 * NSG) {
                int s0 = col[e], s1 = col[e + NSG];
                uint4 v0 = f4[(size_t)s0 * SG + c];
                uint4 v1 = f4[(size_t)s1 * SG + c];
                acc_bf8(acc, v0); acc_bf8(acc, v1);
            }
            if (e < end) {
                uint4 v = f4[(size_t)col[e] * SG + c];
                acc_bf8(acc, v);
            }
#pragma unroll
            for (int j = 0; j < 8; ++j) {
                if (NSG >= 8) acc[j] += __shfl_xor(acc[j], 8, 64);
                acc[j] += __shfl_xor(acc[j], 16, 64);
                acc[j] += __shfl_xor(acc[j], 32, 64);
            }
            if (sg == 0)
                *(uint4*)(sA + (size_t)ln * RS + c * 8) = pack_bf8(acc);
        }
    }
    __syncthreads();

    // ---- phase 2: MFMA conv ----
    f32x4 acc[4][2];
#pragma unroll
    for (int rt = 0; rt < 4; ++rt)
#pragma unroll
        for (int ci = 0; ci < 2; ++ci)
            acc[rt][ci] = (f32x4){0.f, 0.f, 0.f, 0.f};

    int rowIdx[4];
#pragma unroll
    for (int rt = 0; rt < 4; ++rt) {
        int r = n0 + rt * 16 + l16;
        rowIdx[rt] = (r < N) ? r : (N - 1);
    }

    conv_phase_lds<K, RS>(sA, WrP, quad, lane, wv, l16, acc);
    conv_phase_g<K>(X, WoP, rowIdx, quad, lane, wv, acc);

    if (!POOL) {
#pragma unroll
        for (int ci = 0; ci < 2; ++ci) {
            int colg = wv * 32 + ci * 16 + l16;
            float bv = bias[colg];
#pragma unroll
            for (int rt = 0; rt < 4; ++rt) {
                int nbase = n0 + rt * 16 + quad * 4;
#pragma unroll
                for (int r = 0; r < 4; ++r) {
                    int node = nbase + r;
                    if (node < N)
                        outp[(size_t)node * HID_C + colg] = f2bf(fmaxf(acc[rt][ci][r] + bv, 0.f));
                }
            }
        }
    } else {
        // bias + relu in place, then per-graph partial pool
#pragma unroll
        for (int ci = 0; ci < 2; ++ci) {
            float bv = bias[wv * 32 + ci * 16 + l16];
#pragma unroll
            for (int rt = 0; rt < 4; ++rt)
#pragma unroll
                for (int r = 0; r < 4; ++r)
                    acc[rt][ci][r] = fmaxf(acc[rt][ci][r] + bv, 0.f);
        }
        int gmin = sbatch[0];
        int gmax = batch[min(n0 + 63, N - 1)];
        for (int gg = gmin; gg <= gmax; ++gg) {
#pragma unroll
            for (int ci = 0; ci < 2; ++ci) {
                float p = 0.f;
#pragma unroll
                for (int rt = 0; rt < 4; ++rt) {
                    int lbase = rt * 16 + quad * 4;
#pragma unroll
                    for (int r = 0; r < 4; ++r)
                        if (sbatch[lbase + r] == gg) p += acc[rt][ci][r];
                }
                p += __shfl_xor(p, 16, 64);
                p += __shfl_xor(p, 32, 64);
                if (quad == 0)
                    atomicAdd(&pooled[gg * HID_C + wv * 32 + ci * 16 + l16], p);
            }
        }
    }
}

// ---------------------------------------------------------------------------
// Per-graph node counts (batch sorted): run-length per thread, LDS histogram.
// ---------------------------------------------------------------------------
__global__ __launch_bounds__(256) void count_kernel(
    const int* __restrict__ batch, float* __restrict__ cnts, int N)
{
    __shared__ int h[N_GRAPHS_C];
    int t = threadIdx.x;
    if (t < N_GRAPHS_C) h[t] = 0;
    __syncthreads();
    int base = (blockIdx.x * 256 + t) * 16;
    int cur = -1, c = 0;
    for (int i = 0; i < 16; ++i) {
        int n = base + i;
        if (n < N) {
            int g = batch[n];
            if (g != cur) {
                if (cur >= 0) atomicAdd(&h[cur], c);
                cur = g; c = 0;
            }
            ++c;
        }
    }
    if (cur >= 0) atomicAdd(&h[cur], c);
    __syncthreads();
    if (t < N_GRAPHS_C && h[t]) atomicAdd(&cnts[t], (float)h[t]);
}

// ---------------------------------------------------------------------------
// Head: mean, fc1+relu, fc2, softmax (all fp32). One block per graph.
// ---------------------------------------------------------------------------
__global__ __launch_bounds__(128) void head_kernel(
    const float* __restrict__ pooled, const float* __restrict__ cnts,
    const float* __restrict__ fc1w, const float* __restrict__ fc1b,
    const float* __restrict__ fc2w, const float* __restrict__ fc2b,
    float* __restrict__ out)
{
    __shared__ float sp[HID_C];
    __shared__ float so[HID_C];
    __shared__ float sl[64];
    __shared__ float sred[2];
    int g = blockIdx.x;
    int j = threadIdx.x;

    float inv = 1.f / fmaxf(cnts[g], 1.f);
    sp[j] = pooled[g * HID_C + j] * inv;
    __syncthreads();

    float a = fc1b[j];
    for (int k = 0; k < HID_C; ++k) a = fmaf(sp[k], fc1w[k * HID_C + j], a);
    so[j] = fmaxf(a, 0.f);
    __syncthreads();

    if (j < N_ASSETS_C) {
        float l = fc2b[j];
        for (int k = 0; k < HID_C; ++k) l = fmaf(so[k], fc2w[k * N_ASSETS_C + j], l);
        sl[j] = l;
    }
    __syncthreads();

    if (j == 0) {
        float m = -1e30f;
        for (int q = 0; q < N_ASSETS_C; ++q) m = fmaxf(m, sl[q]);
        sred[0] = m;
    }
    __syncthreads();
    if (j < N_ASSETS_C) sl[j] = expf(sl[j] - sred[0]);
    __syncthreads();
    if (j == 0) {
        float s = 0.f;
        for (int q = 0; q < N_ASSETS_C; ++q) s += sl[q];
        sred[1] = 1.f / s;
    }
    __syncthreads();
    if (j < N_ASSETS_C) out[g * N_ASSETS_C + j] = sl[j] * sred[1];
}

// ---------------------------------------------------------------------------
extern "C" void kernel_launch(void* const* d_in, const int* in_sizes, int n_in,
                              void* d_out, int out_size, void* d_ws, size_t ws_size,
                              hipStream_t stream)
{
    const float* x       = (const float*)d_in[0];
    const int*   ei      = (const int*)d_in[1];
    const int*   batch   = (const int*)d_in[2];
    const float* w1_rel  = (const float*)d_in[3];
    const float* b1      = (const float*)d_in[4];
    const float* w1_root = (const float*)d_in[5];
    const float* w2_rel  = (const float*)d_in[6];
    const float* b2      = (const float*)d_in[7];
    const float* w2_root = (const float*)d_in[8];
    const float* fc1w    = (const float*)d_in[9];
    const float* fc1b    = (const float*)d_in[10];
    const float* fc2w    = (const float*)d_in[11];
    const float* fc2b    = (const float*)d_in[12];
    float* out = (float*)d_out;

    char* ws = (char*)d_ws;
    unsigned*       tmp     = (unsigned*)(ws + 0);              //  6,400,000
    int*            col     = (int*)(ws + 6400000);             //  6,400,000
    int*            row_ptr = (int*)(ws + 12800000);            //    400,016
    int*            bbase   = (int*)(ws + 13200016);            //        800
    int*            gcur    = (int*)(ws + 13200816);            //        800
    unsigned short* wp1r    = (unsigned short*)(ws + 13201616); //     32,768
    unsigned short* wp1o    = (unsigned short*)(ws + 13234384); //     32,768
    unsigned short* wp2r    = (unsigned short*)(ws + 13267152); //     65,536
    unsigned short* wp2o    = (unsigned short*)(ws + 13332688); //     65,536
    float*          pooled  = (float*)(ws + 13398224);          //     32,768
    float*          cnts    = (float*)(ws + 13430992);          //        256
    int*            bcnt    = (int*)(ws + 13431248);            //        800
    unsigned short* xb      = (unsigned short*)(ws + 13432048); // 12,800,000
    unsigned short* h1b     = (unsigned short*)(ws + 26232048); // 25,600,000

    // pooled + cnts + bcnt contiguous: one memset
    hipMemsetAsync(pooled, 0, 33824, stream);

    // ---- cast + weight packing (1 launch) ----
    cast_bf16_kernel<<<(N_NODES_C * IN_DIM_C / 4 + 255) / 256, 256, 0, stream>>>(x, xb, N_NODES_C * IN_DIM_C / 4);
    pack_all_kernel<<<96, 64, 0, stream>>>(w1_rel, w1_root, w2_rel, w2_root,
                                           wp1r, wp1o, wp2r, wp2o);

    // ---- per-graph counts (independent) ----
    count_kernel<<<(N_NODES_C + 4095) / 4096, 256, 0, stream>>>(batch, cnts, N_NODES_C);

    // ---- CSR build (bucketed counting sort) ----
    bucket_hist_kernel<<<(N_EDGES_C + 2047) / 2048, 256, 0, stream>>>(ei, bcnt);
    bucket_scan_kernel<<<1, 256, 0, stream>>>(bcnt, bbase, gcur);
    partition_kernel<<<NBLK_A, 256, 0, stream>>>(ei, gcur, tmp);
    bucket_sort_kernel<<<NB_BKT, 256, 0, stream>>>(tmp, bbase, row_ptr, col);

    const int cgrid = (N_NODES_C + 63) / 64;     // 1563

    // ---- Layer 1: fused gather+conv, bf16 out ----
    fused_conv_kernel<IN_DIM_C, false><<<cgrid, 256, 0, stream>>>(
        xb, xb, row_ptr, col, wp1r, wp1o, b1, batch, pooled, h1b, N_NODES_C);

    // ---- Layer 2: fused gather+conv+pool ----
    fused_conv_kernel<HID_C, true><<<cgrid, 256, 0, stream>>>(
        h1b, h1b, row_ptr, col, wp2r, wp2o, b2, batch, pooled, h1b, N_NODES_C);

    // ---- Head ----
    head_kernel<<<N_GRAPHS_C, 128, 0, stream>>>(pooled, cnts, fc1w, fc1b, fc2w, fc2b, out);
}

// Round 9
// 357.299 us; speedup vs baseline: 1.0909x; 1.0909x over previous
//
#include <hip/hip_runtime.h>
#include <math.h>

#define N_NODES_C 100000
#define N_EDGES_C 1600000
#define IN_DIM_C 64
#define HID_C 128
#define N_ASSETS_C 50
#define N_GRAPHS_C 64

#define BKT_SHIFT 9
#define BKT_NODES 512
#define NB_BKT ((N_NODES_C + BKT_NODES - 1) / BKT_NODES)   // 196
#define EPB_A 4096
#define NBLK_A ((N_EDGES_C + EPB_A - 1) / EPB_A)            // 391

// preproc block ranges
#define PP_CAST_NB 6250                       // cast: 1.6M float4 / 256
#define PP_PACK_NB 96
#define PP_CNT_NB 25                          // count: 100000 / (256*16)
#define PP_HIST_NB 782                        // hist: 1.6M / 2048
#define PP_NB (PP_CAST_NB + PP_PACK_NB + PP_CNT_NB + PP_HIST_NB)

typedef __attribute__((ext_vector_type(8))) short bf16x8;
typedef __attribute__((ext_vector_type(4))) float f32x4;

__device__ __forceinline__ unsigned short f2bf(float f) {
    unsigned u = __float_as_uint(f);
    return (unsigned short)((u + 0x7FFFu + ((u >> 16) & 1u)) >> 16);
}
__device__ __forceinline__ float bf2f(unsigned short b) {
    return __uint_as_float((unsigned)b << 16);
}
__device__ __forceinline__ void acc_bf8(float* acc, uint4 v) {
    acc[0] += __uint_as_float(v.x << 16);
    acc[1] += __uint_as_float(v.x & 0xFFFF0000u);
    acc[2] += __uint_as_float(v.y << 16);
    acc[3] += __uint_as_float(v.y & 0xFFFF0000u);
    acc[4] += __uint_as_float(v.z << 16);
    acc[5] += __uint_as_float(v.z & 0xFFFF0000u);
    acc[6] += __uint_as_float(v.w << 16);
    acc[7] += __uint_as_float(v.w & 0xFFFF0000u);
}
__device__ __forceinline__ uint4 pack_bf8v(const float* acc) {
    uint4 o;
    o.x = (unsigned)f2bf(acc[0]) | ((unsigned)f2bf(acc[1]) << 16);
    o.y = (unsigned)f2bf(acc[2]) | ((unsigned)f2bf(acc[3]) << 16);
    o.z = (unsigned)f2bf(acc[4]) | ((unsigned)f2bf(acc[5]) << 16);
    o.w = (unsigned)f2bf(acc[6]) | ((unsigned)f2bf(acc[7]) << 16);
    return o;
}

// ---------------------------------------------------------------------------
// Weight packing body: fp32 [Kw x 128] -> MFMA B-fragments, split hi/lo bf16.
// ---------------------------------------------------------------------------
__device__ __forceinline__ void pack_w_body(
    const float* __restrict__ W, unsigned short* __restrict__ dst, int bid, int lane)
{
    int kc = bid >> 3;
    int ct = bid & 7;
    int quad = lane >> 4;
    int l16 = lane & 15;
    unsigned short hi[8], lo[8];
#pragma unroll
    for (int j = 0; j < 8; ++j) {
        float w = W[(size_t)(kc * 32 + quad * 8 + j) * HID_C + ct * 16 + l16];
        unsigned short h = f2bf(w);
        float r = w - bf2f(h);
        hi[j] = h;
        lo[j] = f2bf(r);
    }
    size_t base = ((size_t)(kc * 8 + ct) * 2) * 512 + (size_t)lane * 8;
#pragma unroll
    for (int j = 0; j < 8; ++j) {
        dst[base + j] = hi[j];
        dst[base + 512 + j] = lo[j];
    }
}

// ---------------------------------------------------------------------------
// Merged preprocessing: cast x->bf16 | pack 4 weights | per-graph counts |
// bucket histogram. One launch, block-range dispatch.
// ---------------------------------------------------------------------------
__global__ __launch_bounds__(256) void preproc_kernel(
    const float* __restrict__ x, unsigned short* __restrict__ xb,
    const float* __restrict__ w1r, const float* __restrict__ w1o,
    const float* __restrict__ w2r, const float* __restrict__ w2o,
    unsigned short* __restrict__ p1r, unsigned short* __restrict__ p1o,
    unsigned short* __restrict__ p2r, unsigned short* __restrict__ p2o,
    const int* __restrict__ batch, float* __restrict__ cnts,
    const int* __restrict__ ei, int* __restrict__ bcnt)
{
    __shared__ int sh[NB_BKT];
    const int b = blockIdx.x;
    const int t = threadIdx.x;

    if (b < PP_CAST_NB) {
        int i = b * 256 + t;                      // < 1,600,000 exactly
        float4 v = ((const float4*)x)[i];
        ushort4 o;
        o.x = f2bf(v.x); o.y = f2bf(v.y); o.z = f2bf(v.z); o.w = f2bf(v.w);
        ((ushort4*)xb)[i] = o;
        return;
    }
    if (b < PP_CAST_NB + PP_PACK_NB) {
        if (t < 64) {
            int pb = b - PP_CAST_NB;
            if (pb < 16)       pack_w_body(w1r, p1r, pb, t);
            else if (pb < 32)  pack_w_body(w1o, p1o, pb - 16, t);
            else if (pb < 64)  pack_w_body(w2r, p2r, pb - 32, t);
            else               pack_w_body(w2o, p2o, pb - 64, t);
        }
        return;
    }
    if (b < PP_CAST_NB + PP_PACK_NB + PP_CNT_NB) {
        if (t < N_GRAPHS_C) sh[t] = 0;
        __syncthreads();
        int base = ((b - PP_CAST_NB - PP_PACK_NB) * 256 + t) * 16;
        int cur = -1, c = 0;
        for (int i = 0; i < 16; ++i) {
            int n = base + i;
            if (n < N_NODES_C) {
                int g = batch[n];
                if (g != cur) {
                    if (cur >= 0) atomicAdd(&sh[cur], c);
                    cur = g; c = 0;
                }
                ++c;
            }
        }
        if (cur >= 0) atomicAdd(&sh[cur], c);
        __syncthreads();
        if (t < N_GRAPHS_C && sh[t]) atomicAdd(&cnts[t], (float)sh[t]);
        return;
    }
    // histogram
    {
        for (int i = t; i < NB_BKT; i += 256) sh[i] = 0;
        __syncthreads();
        int base = (b - PP_CAST_NB - PP_PACK_NB - PP_CNT_NB) * 2048;
#pragma unroll
        for (int i = 0; i < 8; ++i) {
            int e = base + i * 256 + t;
            if (e < N_EDGES_C) {
                int dst = ei[N_EDGES_C + e];
                atomicAdd(&sh[dst >> BKT_SHIFT], 1);
            }
        }
        __syncthreads();
        for (int i = t; i < NB_BKT; i += 256)
            if (sh[i]) atomicAdd(&bcnt[i], sh[i]);
    }
}

// ---------------------------------------------------------------------------
// Scan bucket counts -> bbase (exclusive) + init gcur.
// ---------------------------------------------------------------------------
__global__ __launch_bounds__(256) void bucket_scan_kernel(
    const int* __restrict__ bcnt, int* __restrict__ bbase, int* __restrict__ gcur)
{
    __shared__ int s[256];
    int t = threadIdx.x;
    int v = (t < NB_BKT) ? bcnt[t] : 0;
    s[t] = v;
    __syncthreads();
    for (int o = 1; o < 256; o <<= 1) {
        int x = (t >= o) ? s[t - o] : 0;
        __syncthreads();
        s[t] += x;
        __syncthreads();
    }
    int excl = s[t] - v;
    if (t < NB_BKT) { bbase[t] = excl; gcur[t] = excl; }
    if (t == 255) bbase[NB_BKT] = s[255];
}

// ---------------------------------------------------------------------------
// Pass A: bucket-partition edges into tmp (coalesced run writes).
// EPB 4096 -> 44 KB LDS -> ~3 blocks/CU, 391 blocks.
// ---------------------------------------------------------------------------
__global__ __launch_bounds__(256) void partition_kernel(
    const int* __restrict__ ei, int* __restrict__ gcur,
    unsigned* __restrict__ tmp)
{
    __shared__ unsigned stage[EPB_A];        // 16 KB
    __shared__ unsigned stage2[EPB_A];       // 16 KB
    __shared__ unsigned char sbkt[EPB_A];    // 4 KB
    __shared__ unsigned char sbkt2[EPB_A];   // 4 KB
    __shared__ int cnt[NB_BKT];
    __shared__ int base[NB_BKT];
    __shared__ int cur[NB_BKT];
    __shared__ int gb[NB_BKT];
    __shared__ int s[256];

    const int t = threadIdx.x;
    const int e0 = blockIdx.x * EPB_A;
    const int nE = min(EPB_A, N_EDGES_C - e0);

    for (int i = t; i < NB_BKT; i += 256) cnt[i] = 0;
    __syncthreads();

    for (int idx = t; idx < nE; idx += 256) {
        int e = e0 + idx;
        int src = ei[e];
        int dst = ei[N_EDGES_C + e];
        int b = dst >> BKT_SHIFT;
        stage[idx] = ((unsigned)(dst & (BKT_NODES - 1)) << 17) | (unsigned)src;
        sbkt[idx] = (unsigned char)b;
        atomicAdd(&cnt[b], 1);
    }
    __syncthreads();

    int v = (t < NB_BKT) ? cnt[t] : 0;
    s[t] = v;
    __syncthreads();
    for (int o = 1; o < 256; o <<= 1) {
        int x = (t >= o) ? s[t - o] : 0;
        __syncthreads();
        s[t] += x;
        __syncthreads();
    }
    if (t < NB_BKT) {
        int excl = s[t] - v;
        base[t] = excl;
        cur[t] = excl;
        gb[t] = atomicAdd(&gcur[t], v);
    }
    __syncthreads();

    for (int idx = t; idx < nE; idx += 256) {
        int b = sbkt[idx];
        int p = atomicAdd(&cur[b], 1);
        stage2[p] = stage[idx];
        sbkt2[p] = (unsigned char)b;
    }
    __syncthreads();

    for (int idx = t; idx < nE; idx += 256) {
        int b = sbkt2[idx];
        int dest = gb[b] + (idx - base[b]);
        tmp[dest] = stage2[idx];
    }
}

// ---------------------------------------------------------------------------
// Pass B: per bucket, row_ptr (LDS scan) + dst-sorted col. 512 threads.
// ---------------------------------------------------------------------------
__global__ __launch_bounds__(512) void bucket_sort_kernel(
    const unsigned* __restrict__ tmp, const int* __restrict__ bbase,
    int* __restrict__ row_ptr, int* __restrict__ col)
{
    __shared__ int ldeg[BKT_NODES];   // 512: degree, then cursor
    __shared__ int lsum[512];
    const int t = threadIdx.x;
    const int b = blockIdx.x;
    const int beg = bbase[b];
    const int end = bbase[b + 1];

    ldeg[t] = 0;
    __syncthreads();

    for (int p = beg + t; p < end; p += 512)
        atomicAdd(&ldeg[tmp[p] >> 17], 1);
    __syncthreads();

    int v = ldeg[t];
    lsum[t] = v;
    __syncthreads();
    for (int o = 1; o < 512; o <<= 1) {
        int x = (t >= o) ? lsum[t - o] : 0;
        __syncthreads();
        lsum[t] += x;
        __syncthreads();
    }
    int ep = lsum[t] - v;
    __syncthreads();
    ldeg[t] = ep;        // cursor (relative to beg)

    int gn = b * BKT_NODES + t;
    if (gn < N_NODES_C) row_ptr[gn] = beg + ep;
    if (b == NB_BKT - 1 && t == 0) row_ptr[N_NODES_C] = N_EDGES_C;
    __syncthreads();

    for (int p = beg + t; p < end; p += 512) {
        unsigned u = tmp[p];
        int pos = atomicAdd(&ldeg[u >> 17], 1);
        col[beg + pos] = (int)(u & 0x1FFFFu);
    }
}

// ---------------------------------------------------------------------------
// Gathers (r6-proven): multi-edge lane groups, dwordx4, shfl_xor reduce.
// ---------------------------------------------------------------------------
__global__ __launch_bounds__(256) void gather_bf128_kernel(
    const unsigned short* __restrict__ feat, const int* __restrict__ row_ptr,
    const int* __restrict__ col, unsigned short* __restrict__ agg)
{
    int wave = threadIdx.x >> 6;
    int lane = threadIdx.x & 63;
    int g = lane >> 4;     // edge subgroup 0..3
    int c = lane & 15;     // 16B chunk within row (row = 16 x uint4)
    int n = blockIdx.x * 4 + wave;
    if (n >= N_NODES_C) return;
    int beg = row_ptr[n], end = row_ptr[n + 1];
    const uint4* f4 = (const uint4*)feat;

    float acc[8];
#pragma unroll
    for (int j = 0; j < 8; ++j) acc[j] = 0.f;

    int e = beg + g;
    for (; e + 12 < end; e += 16) {
        int s0 = col[e], s1 = col[e + 4], s2 = col[e + 8], s3 = col[e + 12];
        uint4 v0 = f4[(size_t)s0 * 16 + c];
        uint4 v1 = f4[(size_t)s1 * 16 + c];
        uint4 v2 = f4[(size_t)s2 * 16 + c];
        uint4 v3 = f4[(size_t)s3 * 16 + c];
        acc_bf8(acc, v0); acc_bf8(acc, v1); acc_bf8(acc, v2); acc_bf8(acc, v3);
    }
    if (e + 4 < end) {
        int s0 = col[e], s1 = col[e + 4];
        uint4 v0 = f4[(size_t)s0 * 16 + c];
        uint4 v1 = f4[(size_t)s1 * 16 + c];
        acc_bf8(acc, v0); acc_bf8(acc, v1);
        e += 8;
    }
    if (e < end) {
        uint4 v = f4[(size_t)col[e] * 16 + c];
        acc_bf8(acc, v);
    }
#pragma unroll
    for (int j = 0; j < 8; ++j) {
        acc[j] += __shfl_xor(acc[j], 16, 64);
        acc[j] += __shfl_xor(acc[j], 32, 64);
    }
    if (g == 0)
        ((uint4*)agg)[(size_t)n * 16 + c] = pack_bf8v(acc);
}

__global__ __launch_bounds__(256) void gather_bf64_kernel(
    const unsigned short* __restrict__ feat, const int* __restrict__ row_ptr,
    const int* __restrict__ col, unsigned short* __restrict__ agg)
{
    int wave = threadIdx.x >> 6;
    int lane = threadIdx.x & 63;
    int g = lane >> 3;     // edge subgroup 0..7
    int c = lane & 7;      // 16B chunk within row (row = 8 x uint4)
    int n = blockIdx.x * 4 + wave;
    if (n >= N_NODES_C) return;
    int beg = row_ptr[n], end = row_ptr[n + 1];
    const uint4* f4 = (const uint4*)feat;

    float acc[8];
#pragma unroll
    for (int j = 0; j < 8; ++j) acc[j] = 0.f;

    int e = beg + g;
    for (; e + 8 < end; e += 16) {
        int s0 = col[e], s1 = col[e + 8];
        uint4 v0 = f4[(size_t)s0 * 8 + c];
        uint4 v1 = f4[(size_t)s1 * 8 + c];
        acc_bf8(acc, v0); acc_bf8(acc, v1);
    }
    if (e < end) {
        uint4 v = f4[(size_t)col[e] * 8 + c];
        acc_bf8(acc, v);
    }
#pragma unroll
    for (int j = 0; j < 8; ++j) {
        acc[j] += __shfl_xor(acc[j], 8, 64);
        acc[j] += __shfl_xor(acc[j], 16, 64);
        acc[j] += __shfl_xor(acc[j], 32, 64);
    }
    if (g == 0)
        ((uint4*)agg)[(size_t)n * 8 + c] = pack_bf8v(acc);
}

// ---------------------------------------------------------------------------
// MFMA conv phase: acc += [P rows] @ [WP hi] + [P rows] @ [WP lo]
// ---------------------------------------------------------------------------
template<int K>
__device__ __forceinline__ void conv_phase(
    const unsigned short* __restrict__ P, const unsigned short* __restrict__ WP,
    const int* rowIdx, int quad, int lane, int wv, f32x4 acc[4][2])
{
#pragma unroll
    for (int kc = 0; kc < K / 32; ++kc) {
        bf16x8 afr[4];
#pragma unroll
        for (int rt = 0; rt < 4; ++rt)
            afr[rt] = *(const bf16x8*)(P + (size_t)rowIdx[rt] * K + kc * 32 + quad * 8);
#pragma unroll
        for (int ci = 0; ci < 2; ++ci) {
            int ct = wv * 2 + ci;
            const unsigned short* bp = WP + ((size_t)(kc * 8 + ct) * 2) * 512 + (size_t)lane * 8;
            bf16x8 bhi = *(const bf16x8*)bp;
            bf16x8 blo = *(const bf16x8*)(bp + 512);
#pragma unroll
            for (int rt = 0; rt < 4; ++rt) {
                acc[rt][ci] = __builtin_amdgcn_mfma_f32_16x16x32_bf16(afr[rt], bhi, acc[rt][ci], 0, 0, 0);
                acc[rt][ci] = __builtin_amdgcn_mfma_f32_16x16x32_bf16(afr[rt], blo, acc[rt][ci], 0, 0, 0);
            }
        }
    }
}

// Layer-1 conv: bf16 out.
template<int KA, int KX>
__global__ __launch_bounds__(256) void conv_mfma_kernel(
    const unsigned short* __restrict__ A, const unsigned short* __restrict__ X,
    const unsigned short* __restrict__ WrP, const unsigned short* __restrict__ WoP,
    const float* __restrict__ bias, unsigned short* __restrict__ outp, int N)
{
    const int t = threadIdx.x;
    const int wv = t >> 6;
    const int lane = t & 63;
    const int quad = lane >> 4;
    const int l16 = lane & 15;
    const int n0 = blockIdx.x * 64;

    f32x4 acc[4][2];
#pragma unroll
    for (int rt = 0; rt < 4; ++rt)
#pragma unroll
        for (int ci = 0; ci < 2; ++ci)
            acc[rt][ci] = (f32x4){0.f, 0.f, 0.f, 0.f};

    int rowIdx[4];
#pragma unroll
    for (int rt = 0; rt < 4; ++rt) {
        int r = n0 + rt * 16 + l16;
        rowIdx[rt] = (r < N) ? r : (N - 1);
    }

    conv_phase<KA>(A, WrP, rowIdx, quad, lane, wv, acc);
    conv_phase<KX>(X, WoP, rowIdx, quad, lane, wv, acc);

#pragma unroll
    for (int ci = 0; ci < 2; ++ci) {
        int colg = wv * 32 + ci * 16 + l16;
        float bv = bias[colg];
#pragma unroll
        for (int rt = 0; rt < 4; ++rt) {
            int nbase = n0 + rt * 16 + quad * 4;
#pragma unroll
            for (int r = 0; r < 4; ++r) {
                int node = nbase + r;
                if (node < N)
                    outp[(size_t)node * HID_C + colg] = f2bf(fmaxf(acc[rt][ci][r] + bv, 0.f));
            }
        }
    }
}

// Layer-2 conv with fused mean-pool partials: h2 never materialized.
template<int KA, int KX>
__global__ __launch_bounds__(256) void conv_mfma_pool_kernel(
    const unsigned short* __restrict__ A, const unsigned short* __restrict__ X,
    const unsigned short* __restrict__ WrP, const unsigned short* __restrict__ WoP,
    const float* __restrict__ bias, const int* __restrict__ batch,
    float* __restrict__ pooled, int N)
{
    __shared__ int sbatch[64];
    const int t = threadIdx.x;
    const int wv = t >> 6;
    const int lane = t & 63;
    const int quad = lane >> 4;
    const int l16 = lane & 15;
    const int n0 = blockIdx.x * 64;

    if (t < 64) {
        int node = n0 + t;
        sbatch[t] = (node < N) ? batch[node] : -1;
    }

    f32x4 acc[4][2];
#pragma unroll
    for (int rt = 0; rt < 4; ++rt)
#pragma unroll
        for (int ci = 0; ci < 2; ++ci)
            acc[rt][ci] = (f32x4){0.f, 0.f, 0.f, 0.f};

    int rowIdx[4];
#pragma unroll
    for (int rt = 0; rt < 4; ++rt) {
        int r = n0 + rt * 16 + l16;
        rowIdx[rt] = (r < N) ? r : (N - 1);
    }

    conv_phase<KA>(A, WrP, rowIdx, quad, lane, wv, acc);
    conv_phase<KX>(X, WoP, rowIdx, quad, lane, wv, acc);
    __syncthreads();

    // bias + relu in place
#pragma unroll
    for (int ci = 0; ci < 2; ++ci) {
        float bv = bias[wv * 32 + ci * 16 + l16];
#pragma unroll
        for (int rt = 0; rt < 4; ++rt)
#pragma unroll
            for (int r = 0; r < 4; ++r)
                acc[rt][ci][r] = fmaxf(acc[rt][ci][r] + bv, 0.f);
    }

    int gmin = sbatch[0];
    int gmax = batch[min(n0 + 63, N - 1)];
    for (int gg = gmin; gg <= gmax; ++gg) {
#pragma unroll
        for (int ci = 0; ci < 2; ++ci) {
            float p = 0.f;
#pragma unroll
            for (int rt = 0; rt < 4; ++rt) {
                int lbase = rt * 16 + quad * 4;
#pragma unroll
                for (int r = 0; r < 4; ++r)
                    if (sbatch[lbase + r] == gg) p += acc[rt][ci][r];
            }
            p += __shfl_xor(p, 16, 64);
            p += __shfl_xor(p, 32, 64);
            if (quad == 0)
                atomicAdd(&pooled[gg * HID_C + wv * 32 + ci * 16 + l16], p);
        }
    }
}

// ---------------------------------------------------------------------------
// Head: mean, fc1+relu, fc2, softmax (all fp32). One block per graph.
// ---------------------------------------------------------------------------
__global__ __launch_bounds__(128) void head_kernel(
    const float* __restrict__ pooled, const float* __restrict__ cnts,
    const float* __restrict__ fc1w, const float* __restrict__ fc1b,
    const float* __restrict__ fc2w, const float* __restrict__ fc2b,
    float* __restrict__ out)
{
    __shared__ float sp[HID_C];
    __shared__ float so[HID_C];
    __shared__ float sl[64];
    __shared__ float sred[2];
    int g = blockIdx.x;
    int j = threadIdx.x;

    float inv = 1.f / fmaxf(cnts[g], 1.f);
    sp[j] = pooled[g * HID_C + j] * inv;
    __syncthreads();

    float a = fc1b[j];
    for (int k = 0; k < HID_C; ++k) a = fmaf(sp[k], fc1w[k * HID_C + j], a);
    so[j] = fmaxf(a, 0.f);
    __syncthreads();

    if (j < N_ASSETS_C) {
        float l = fc2b[j];
        for (int k = 0; k < HID_C; ++k) l = fmaf(so[k], fc2w[k * N_ASSETS_C + j], l);
        sl[j] = l;
    }
    __syncthreads();

    if (j == 0) {
        float m = -1e30f;
        for (int q = 0; q < N_ASSETS_C; ++q) m = fmaxf(m, sl[q]);
        sred[0] = m;
    }
    __syncthreads();
    if (j < N_ASSETS_C) sl[j] = expf(sl[j] - sred[0]);
    __syncthreads();
    if (j == 0) {
        float s = 0.f;
        for (int q = 0; q < N_ASSETS_C; ++q) s += sl[q];
        sred[1] = 1.f / s;
    }
    __syncthreads();
    if (j < N_ASSETS_C) out[g * N_ASSETS_C + j] = sl[j] * sred[1];
}

// ---------------------------------------------------------------------------
extern "C" void kernel_launch(void* const* d_in, const int* in_sizes, int n_in,
                              void* d_out, int out_size, void* d_ws, size_t ws_size,
                              hipStream_t stream)
{
    const float* x       = (const float*)d_in[0];
    const int*   ei      = (const int*)d_in[1];
    const int*   batch   = (const int*)d_in[2];
    const float* w1_rel  = (const float*)d_in[3];
    const float* b1      = (const float*)d_in[4];
    const float* w1_root = (const float*)d_in[5];
    const float* w2_rel  = (const float*)d_in[6];
    const float* b2      = (const float*)d_in[7];
    const float* w2_root = (const float*)d_in[8];
    const float* fc1w    = (const float*)d_in[9];
    const float* fc1b    = (const float*)d_in[10];
    const float* fc2w    = (const float*)d_in[11];
    const float* fc2b    = (const float*)d_in[12];
    float* out = (float*)d_out;

    char* ws = (char*)d_ws;
    unsigned*       tmp     = (unsigned*)(ws + 0);              //  6,400,000
    int*            col     = (int*)(ws + 6400000);             //  6,400,000
    int*            row_ptr = (int*)(ws + 12800000);            //    400,016
    int*            bbase   = (int*)(ws + 13200016);            //        800
    int*            gcur    = (int*)(ws + 13200816);            //        800
    unsigned short* wp1r    = (unsigned short*)(ws + 13201616); //     32,768
    unsigned short* wp1o    = (unsigned short*)(ws + 13234384); //     32,768
    unsigned short* wp2r    = (unsigned short*)(ws + 13267152); //     65,536
    unsigned short* wp2o    = (unsigned short*)(ws + 13332688); //     65,536
    float*          pooled  = (float*)(ws + 13398224);          //     32,768
    float*          cnts    = (float*)(ws + 13430992);          //        256
    int*            bcnt    = (int*)(ws + 13431248);            //        800
    unsigned short* xb      = (unsigned short*)(ws + 13432048); // 12,800,000
    unsigned short* agg1b   = (unsigned short*)(ws + 26232048); // 12,800,000
    unsigned short* h1b     = (unsigned short*)(ws + 39032048); // 25,600,000
    unsigned short* agg2b   = (unsigned short*)(ws + 64632048); // 25,600,000

    // pooled + cnts + bcnt contiguous: one memset
    hipMemsetAsync(pooled, 0, 33824, stream);

    // ---- merged preprocessing (cast | pack | count | hist) ----
    preproc_kernel<<<PP_NB, 256, 0, stream>>>(
        x, xb, w1_rel, w1_root, w2_rel, w2_root,
        wp1r, wp1o, wp2r, wp2o, batch, cnts, ei, bcnt);

    // ---- CSR build ----
    bucket_scan_kernel<<<1, 256, 0, stream>>>(bcnt, bbase, gcur);
    partition_kernel<<<NBLK_A, 256, 0, stream>>>(ei, gcur, tmp);
    bucket_sort_kernel<<<NB_BKT, 512, 0, stream>>>(tmp, bbase, row_ptr, col);

    const int ggrid = (N_NODES_C + 3) / 4;       // 25000
    const int cgrid = (N_NODES_C + 63) / 64;     // 1563

    // ---- Layer 1 ----
    gather_bf64_kernel<<<ggrid, 256, 0, stream>>>(xb, row_ptr, col, agg1b);
    conv_mfma_kernel<IN_DIM_C, IN_DIM_C><<<cgrid, 256, 0, stream>>>(
        agg1b, xb, wp1r, wp1o, b1, h1b, N_NODES_C);

    // ---- Layer 2 (pool fused into epilogue) ----
    gather_bf128_kernel<<<ggrid, 256, 0, stream>>>(h1b, row_ptr, col, agg2b);
    conv_mfma_pool_kernel<HID_C, HID_C><<<cgrid, 256, 0, stream>>>(
        agg2b, h1b, wp2r, wp2o, b2, batch, pooled, N_NODES_C);

    // ---- Head ----
    head_kernel<<<N_GRAPHS_C, 128, 0, stream>>>(pooled, cnts, fc1w, fc1b, fc2w, fc2b, out);
}

// Round 10
// 335.288 us; speedup vs baseline: 1.1626x; 1.0656x over previous
//
#include <hip/hip_runtime.h>
#include <math.h>

#define N_NODES_C 100000
#define N_EDGES_C 1600000
#define IN_DIM_C 64
#define HID_C 128
#define N_ASSETS_C 50
#define N_GRAPHS_C 64

#define BKT_SHIFT 9
#define BKT_NODES 512
#define NB_BKT ((N_NODES_C + BKT_NODES - 1) / BKT_NODES)   // 196
#define EPB_A 8192
#define NBLK_A ((N_EDGES_C + EPB_A - 1) / EPB_A)            // 196

// preproc block ranges (cast | pack | count) -- hist kept separate (r6-exact)
#define PP_CAST_NB 6250                       // 1.6M float4 / 256
#define PP_PACK_NB 96
#define PP_CNT_NB 25                          // 100000 / (256*16)
#define PP_NB (PP_CAST_NB + PP_PACK_NB + PP_CNT_NB)

typedef __attribute__((ext_vector_type(8))) short bf16x8;
typedef __attribute__((ext_vector_type(4))) float f32x4;

__device__ __forceinline__ unsigned short f2bf(float f) {
    unsigned u = __float_as_uint(f);
    return (unsigned short)((u + 0x7FFFu + ((u >> 16) & 1u)) >> 16);
}
__device__ __forceinline__ float bf2f(unsigned short b) {
    return __uint_as_float((unsigned)b << 16);
}
__device__ __forceinline__ void acc_bf8(float* acc, uint4 v) {
    acc[0] += __uint_as_float(v.x << 16);
    acc[1] += __uint_as_float(v.x & 0xFFFF0000u);
    acc[2] += __uint_as_float(v.y << 16);
    acc[3] += __uint_as_float(v.y & 0xFFFF0000u);
    acc[4] += __uint_as_float(v.z << 16);
    acc[5] += __uint_as_float(v.z & 0xFFFF0000u);
    acc[6] += __uint_as_float(v.w << 16);
    acc[7] += __uint_as_float(v.w & 0xFFFF0000u);
}

// ---------------------------------------------------------------------------
// Weight packing body: fp32 [Kw x 128] -> MFMA B-fragments, split hi/lo bf16.
// ---------------------------------------------------------------------------
__device__ __forceinline__ void pack_w_body(
    const float* __restrict__ W, unsigned short* __restrict__ dst, int bid, int lane)
{
    int kc = bid >> 3;
    int ct = bid & 7;
    int quad = lane >> 4;
    int l16 = lane & 15;
    unsigned short hi[8], lo[8];
#pragma unroll
    for (int j = 0; j < 8; ++j) {
        float w = W[(size_t)(kc * 32 + quad * 8 + j) * HID_C + ct * 16 + l16];
        unsigned short h = f2bf(w);
        float r = w - bf2f(h);
        hi[j] = h;
        lo[j] = f2bf(r);
    }
    size_t base = ((size_t)(kc * 8 + ct) * 2) * 512 + (size_t)lane * 8;
#pragma unroll
    for (int j = 0; j < 8; ++j) {
        dst[base + j] = hi[j];
        dst[base + 512 + j] = lo[j];
    }
}

// ---------------------------------------------------------------------------
// Merged preprocessing: cast x->bf16 | pack 4 weights | per-graph counts.
// Touches only x/weights/batch/xb/cnts -- fully decoupled from CSR + gathers.
// ---------------------------------------------------------------------------
__global__ __launch_bounds__(256) void preproc_kernel(
    const float* __restrict__ x, unsigned short* __restrict__ xb,
    const float* __restrict__ w1r, const float* __restrict__ w1o,
    const float* __restrict__ w2r, const float* __restrict__ w2o,
    unsigned short* __restrict__ p1r, unsigned short* __restrict__ p1o,
    unsigned short* __restrict__ p2r, unsigned short* __restrict__ p2o,
    const int* __restrict__ batch, float* __restrict__ cnts)
{
    __shared__ int sh[N_GRAPHS_C];
    const int b = blockIdx.x;
    const int t = threadIdx.x;

    if (b < PP_CAST_NB) {
        int i = b * 256 + t;                      // < 1,600,000 exactly
        float4 v = ((const float4*)x)[i];
        ushort4 o;
        o.x = f2bf(v.x); o.y = f2bf(v.y); o.z = f2bf(v.z); o.w = f2bf(v.w);
        ((ushort4*)xb)[i] = o;
        return;
    }
    if (b < PP_CAST_NB + PP_PACK_NB) {
        if (t < 64) {
            int pb = b - PP_CAST_NB;
            if (pb < 16)       pack_w_body(w1r, p1r, pb, t);
            else if (pb < 32)  pack_w_body(w1o, p1o, pb - 16, t);
            else if (pb < 64)  pack_w_body(w2r, p2r, pb - 32, t);
            else               pack_w_body(w2o, p2o, pb - 64, t);
        }
        return;
    }
    // per-graph counts
    if (t < N_GRAPHS_C) sh[t] = 0;
    __syncthreads();
    int base = ((b - PP_CAST_NB - PP_PACK_NB) * 256 + t) * 16;
    int cur = -1, c = 0;
    for (int i = 0; i < 16; ++i) {
        int n = base + i;
        if (n < N_NODES_C) {
            int g = batch[n];
            if (g != cur) {
                if (cur >= 0) atomicAdd(&sh[cur], c);
                cur = g; c = 0;
            }
            ++c;
        }
    }
    if (cur >= 0) atomicAdd(&sh[cur], c);
    __syncthreads();
    if (t < N_GRAPHS_C && sh[t]) atomicAdd(&cnts[t], (float)sh[t]);
}

// ---------------------------------------------------------------------------
// CSR build: bucketed counting sort (r6-exact).
// ---------------------------------------------------------------------------
__global__ __launch_bounds__(256) void bucket_hist_kernel(
    const int* __restrict__ ei, int* __restrict__ bcnt)
{
    __shared__ int cnt[NB_BKT];
    int t = threadIdx.x;
    for (int i = t; i < NB_BKT; i += 256) cnt[i] = 0;
    __syncthreads();
    int base = blockIdx.x * 2048;
#pragma unroll
    for (int i = 0; i < 8; ++i) {
        int e = base + i * 256 + t;
        if (e < N_EDGES_C) {
            int dst = ei[N_EDGES_C + e];
            atomicAdd(&cnt[dst >> BKT_SHIFT], 1);
        }
    }
    __syncthreads();
    for (int i = t; i < NB_BKT; i += 256)
        if (cnt[i]) atomicAdd(&bcnt[i], cnt[i]);
}

__global__ __launch_bounds__(256) void bucket_scan_kernel(
    const int* __restrict__ bcnt, int* __restrict__ bbase, int* __restrict__ gcur)
{
    __shared__ int s[256];
    int t = threadIdx.x;
    int v = (t < NB_BKT) ? bcnt[t] : 0;
    s[t] = v;
    __syncthreads();
    for (int o = 1; o < 256; o <<= 1) {
        int x = (t >= o) ? s[t - o] : 0;
        __syncthreads();
        s[t] += x;
        __syncthreads();
    }
    int excl = s[t] - v;
    if (t < NB_BKT) { bbase[t] = excl; gcur[t] = excl; }
    if (t == 255) bbase[NB_BKT] = s[255];
}

__global__ __launch_bounds__(256) void partition_kernel(
    const int* __restrict__ ei, int* __restrict__ gcur,
    unsigned* __restrict__ tmp)
{
    __shared__ unsigned stage[EPB_A];
    __shared__ unsigned stage2[EPB_A];
    __shared__ unsigned char sbkt[EPB_A];
    __shared__ unsigned char sbkt2[EPB_A];
    __shared__ int cnt[NB_BKT];
    __shared__ int base[NB_BKT];
    __shared__ int cur[NB_BKT];
    __shared__ int gb[NB_BKT];
    __shared__ int s[256];

    const int t = threadIdx.x;
    const int e0 = blockIdx.x * EPB_A;
    const int nE = min(EPB_A, N_EDGES_C - e0);

    for (int i = t; i < NB_BKT; i += 256) cnt[i] = 0;
    __syncthreads();

    for (int idx = t; idx < nE; idx += 256) {
        int e = e0 + idx;
        int src = ei[e];
        int dst = ei[N_EDGES_C + e];
        int b = dst >> BKT_SHIFT;
        stage[idx] = ((unsigned)(dst & (BKT_NODES - 1)) << 17) | (unsigned)src;
        sbkt[idx] = (unsigned char)b;
        atomicAdd(&cnt[b], 1);
    }
    __syncthreads();

    int v = (t < NB_BKT) ? cnt[t] : 0;
    s[t] = v;
    __syncthreads();
    for (int o = 1; o < 256; o <<= 1) {
        int x = (t >= o) ? s[t - o] : 0;
        __syncthreads();
        s[t] += x;
        __syncthreads();
    }
    if (t < NB_BKT) {
        int excl = s[t] - v;
        base[t] = excl;
        cur[t] = excl;
        gb[t] = atomicAdd(&gcur[t], v);
    }
    __syncthreads();

    for (int idx = t; idx < nE; idx += 256) {
        int b = sbkt[idx];
        int p = atomicAdd(&cur[b], 1);
        stage2[p] = stage[idx];
        sbkt2[p] = (unsigned char)b;
    }
    __syncthreads();

    for (int idx = t; idx < nE; idx += 256) {
        int b = sbkt2[idx];
        int dest = gb[b] + (idx - base[b]);
        tmp[dest] = stage2[idx];
    }
}

__global__ __launch_bounds__(256) void bucket_sort_kernel(
    const unsigned* __restrict__ tmp, const int* __restrict__ bbase,
    int* __restrict__ row_ptr, int* __restrict__ col)
{
    __shared__ int ldeg[BKT_NODES];
    __shared__ int lsum[256];
    const int t = threadIdx.x;
    const int b = blockIdx.x;
    const int beg = bbase[b];
    const int end = bbase[b + 1];

    ldeg[t] = 0; ldeg[t + 256] = 0;
    __syncthreads();

    for (int p = beg + t; p < end; p += 256)
        atomicAdd(&ldeg[tmp[p] >> 17], 1);
    __syncthreads();

    int a0 = ldeg[2 * t], a1 = ldeg[2 * t + 1];
    int pair = a0 + a1;
    lsum[t] = pair;
    __syncthreads();
    for (int o = 1; o < 256; o <<= 1) {
        int x = (t >= o) ? lsum[t - o] : 0;
        __syncthreads();
        lsum[t] += x;
        __syncthreads();
    }
    int ep = lsum[t] - pair;
    __syncthreads();
    ldeg[2 * t] = ep;
    ldeg[2 * t + 1] = ep + a0;

    int gn0 = b * BKT_NODES + 2 * t;
    if (gn0 < N_NODES_C)     row_ptr[gn0] = beg + ep;
    if (gn0 + 1 < N_NODES_C) row_ptr[gn0 + 1] = beg + ep + a0;
    if (b == NB_BKT - 1 && t == 0) row_ptr[N_NODES_C] = N_EDGES_C;
    __syncthreads();

    for (int p = beg + t; p < end; p += 256) {
        unsigned v = tmp[p];
        int pos = atomicAdd(&ldeg[v >> 17], 1);
        col[beg + pos] = (int)(v & 0x1FFFFu);
    }
}

// ---------------------------------------------------------------------------
// Gathers (r6-exact): multi-edge lane groups, dwordx4, shfl_xor reduce.
// ---------------------------------------------------------------------------
__global__ __launch_bounds__(256) void gather_bf128_kernel(
    const unsigned short* __restrict__ feat, const int* __restrict__ row_ptr,
    const int* __restrict__ col, unsigned short* __restrict__ agg)
{
    int wave = threadIdx.x >> 6;
    int lane = threadIdx.x & 63;
    int g = lane >> 4;     // edge subgroup 0..3
    int c = lane & 15;     // 16B chunk within row (row = 16 x uint4)
    int n = blockIdx.x * 4 + wave;
    if (n >= N_NODES_C) return;
    int beg = row_ptr[n], end = row_ptr[n + 1];
    const uint4* f4 = (const uint4*)feat;

    float acc[8];
#pragma unroll
    for (int j = 0; j < 8; ++j) acc[j] = 0.f;

    int e = beg + g;
    for (; e + 12 < end; e += 16) {
        int s0 = col[e], s1 = col[e + 4], s2 = col[e + 8], s3 = col[e + 12];
        uint4 v0 = f4[(size_t)s0 * 16 + c];
        uint4 v1 = f4[(size_t)s1 * 16 + c];
        uint4 v2 = f4[(size_t)s2 * 16 + c];
        uint4 v3 = f4[(size_t)s3 * 16 + c];
        acc_bf8(acc, v0); acc_bf8(acc, v1); acc_bf8(acc, v2); acc_bf8(acc, v3);
    }
    if (e + 4 < end) {
        int s0 = col[e], s1 = col[e + 4];
        uint4 v0 = f4[(size_t)s0 * 16 + c];
        uint4 v1 = f4[(size_t)s1 * 16 + c];
        acc_bf8(acc, v0); acc_bf8(acc, v1);
        e += 8;
    }
    if (e < end) {
        uint4 v = f4[(size_t)col[e] * 16 + c];
        acc_bf8(acc, v);
    }
#pragma unroll
    for (int j = 0; j < 8; ++j) {
        acc[j] += __shfl_xor(acc[j], 16, 64);
        acc[j] += __shfl_xor(acc[j], 32, 64);
    }
    if (g == 0) {
        uint4 o;
        o.x = (unsigned)f2bf(acc[0]) | ((unsigned)f2bf(acc[1]) << 16);
        o.y = (unsigned)f2bf(acc[2]) | ((unsigned)f2bf(acc[3]) << 16);
        o.z = (unsigned)f2bf(acc[4]) | ((unsigned)f2bf(acc[5]) << 16);
        o.w = (unsigned)f2bf(acc[6]) | ((unsigned)f2bf(acc[7]) << 16);
        ((uint4*)agg)[(size_t)n * 16 + c] = o;
    }
}

__global__ __launch_bounds__(256) void gather_bf64_kernel(
    const unsigned short* __restrict__ feat, const int* __restrict__ row_ptr,
    const int* __restrict__ col, unsigned short* __restrict__ agg)
{
    int wave = threadIdx.x >> 6;
    int lane = threadIdx.x & 63;
    int g = lane >> 3;     // edge subgroup 0..7
    int c = lane & 7;      // 16B chunk within row (row = 8 x uint4)
    int n = blockIdx.x * 4 + wave;
    if (n >= N_NODES_C) return;
    int beg = row_ptr[n], end = row_ptr[n + 1];
    const uint4* f4 = (const uint4*)feat;

    float acc[8];
#pragma unroll
    for (int j = 0; j < 8; ++j) acc[j] = 0.f;

    int e = beg + g;
    for (; e + 8 < end; e += 16) {
        int s0 = col[e], s1 = col[e + 8];
        uint4 v0 = f4[(size_t)s0 * 8 + c];
        uint4 v1 = f4[(size_t)s1 * 8 + c];
        acc_bf8(acc, v0); acc_bf8(acc, v1);
    }
    if (e < end) {
        uint4 v = f4[(size_t)col[e] * 8 + c];
        acc_bf8(acc, v);
    }
#pragma unroll
    for (int j = 0; j < 8; ++j) {
        acc[j] += __shfl_xor(acc[j], 8, 64);
        acc[j] += __shfl_xor(acc[j], 16, 64);
        acc[j] += __shfl_xor(acc[j], 32, 64);
    }
    if (g == 0) {
        uint4 o;
        o.x = (unsigned)f2bf(acc[0]) | ((unsigned)f2bf(acc[1]) << 16);
        o.y = (unsigned)f2bf(acc[2]) | ((unsigned)f2bf(acc[3]) << 16);
        o.z = (unsigned)f2bf(acc[4]) | ((unsigned)f2bf(acc[5]) << 16);
        o.w = (unsigned)f2bf(acc[6]) | ((unsigned)f2bf(acc[7]) << 16);
        ((uint4*)agg)[(size_t)n * 8 + c] = o;
    }
}

// ---------------------------------------------------------------------------
// MFMA conv phase: acc += [P rows] @ [WP hi] + [P rows] @ [WP lo]
// ---------------------------------------------------------------------------
template<int K>
__device__ __forceinline__ void conv_phase(
    const unsigned short* __restrict__ P, const unsigned short* __restrict__ WP,
    const int* rowIdx, int quad, int lane, int wv, f32x4 acc[4][2])
{
#pragma unroll
    for (int kc = 0; kc < K / 32; ++kc) {
        bf16x8 afr[4];
#pragma unroll
        for (int rt = 0; rt < 4; ++rt)
            afr[rt] = *(const bf16x8*)(P + (size_t)rowIdx[rt] * K + kc * 32 + quad * 8);
#pragma unroll
        for (int ci = 0; ci < 2; ++ci) {
            int ct = wv * 2 + ci;
            const unsigned short* bp = WP + ((size_t)(kc * 8 + ct) * 2) * 512 + (size_t)lane * 8;
            bf16x8 bhi = *(const bf16x8*)bp;
            bf16x8 blo = *(const bf16x8*)(bp + 512);
#pragma unroll
            for (int rt = 0; rt < 4; ++rt) {
                acc[rt][ci] = __builtin_amdgcn_mfma_f32_16x16x32_bf16(afr[rt], bhi, acc[rt][ci], 0, 0, 0);
                acc[rt][ci] = __builtin_amdgcn_mfma_f32_16x16x32_bf16(afr[rt], blo, acc[rt][ci], 0, 0, 0);
            }
        }
    }
}

// Layer-1 conv: bf16 out.
template<int KA, int KX>
__global__ __launch_bounds__(256) void conv_mfma_kernel(
    const unsigned short* __restrict__ A, const unsigned short* __restrict__ X,
    const unsigned short* __restrict__ WrP, const unsigned short* __restrict__ WoP,
    const float* __restrict__ bias, unsigned short* __restrict__ outp, int N)
{
    const int t = threadIdx.x;
    const int wv = t >> 6;
    const int lane = t & 63;
    const int quad = lane >> 4;
    const int l16 = lane & 15;
    const int n0 = blockIdx.x * 64;

    f32x4 acc[4][2];
#pragma unroll
    for (int rt = 0; rt < 4; ++rt)
#pragma unroll
        for (int ci = 0; ci < 2; ++ci)
            acc[rt][ci] = (f32x4){0.f, 0.f, 0.f, 0.f};

    int rowIdx[4];
#pragma unroll
    for (int rt = 0; rt < 4; ++rt) {
        int r = n0 + rt * 16 + l16;
        rowIdx[rt] = (r < N) ? r : (N - 1);
    }

    conv_phase<KA>(A, WrP, rowIdx, quad, lane, wv, acc);
    conv_phase<KX>(X, WoP, rowIdx, quad, lane, wv, acc);

#pragma unroll
    for (int ci = 0; ci < 2; ++ci) {
        int colg = wv * 32 + ci * 16 + l16;
        float bv = bias[colg];
#pragma unroll
        for (int rt = 0; rt < 4; ++rt) {
            int nbase = n0 + rt * 16 + quad * 4;
#pragma unroll
            for (int r = 0; r < 4; ++r) {
                int node = nbase + r;
                if (node < N)
                    outp[(size_t)node * HID_C + colg] = f2bf(fmaxf(acc[rt][ci][r] + bv, 0.f));
            }
        }
    }
}

// Layer-2 conv with fused mean-pool partials: h2 never materialized.
template<int KA, int KX>
__global__ __launch_bounds__(256) void conv_mfma_pool_kernel(
    const unsigned short* __restrict__ A, const unsigned short* __restrict__ X,
    const unsigned short* __restrict__ WrP, const unsigned short* __restrict__ WoP,
    const float* __restrict__ bias, const int* __restrict__ batch,
    float* __restrict__ pooled, int N)
{
    __shared__ int sbatch[64];
    const int t = threadIdx.x;
    const int wv = t >> 6;
    const int lane = t & 63;
    const int quad = lane >> 4;
    const int l16 = lane & 15;
    const int n0 = blockIdx.x * 64;

    if (t < 64) {
        int node = n0 + t;
        sbatch[t] = (node < N) ? batch[node] : -1;
    }

    f32x4 acc[4][2];
#pragma unroll
    for (int rt = 0; rt < 4; ++rt)
#pragma unroll
        for (int ci = 0; ci < 2; ++ci)
            acc[rt][ci] = (f32x4){0.f, 0.f, 0.f, 0.f};

    int rowIdx[4];
#pragma unroll
    for (int rt = 0; rt < 4; ++rt) {
        int r = n0 + rt * 16 + l16;
        rowIdx[rt] = (r < N) ? r : (N - 1);
    }

    conv_phase<KA>(A, WrP, rowIdx, quad, lane, wv, acc);
    conv_phase<KX>(X, WoP, rowIdx, quad, lane, wv, acc);
    __syncthreads();

    // bias + relu in place
#pragma unroll
    for (int ci = 0; ci < 2; ++ci) {
        float bv = bias[wv * 32 + ci * 16 + l16];
#pragma unroll
        for (int rt = 0; rt < 4; ++rt)
#pragma unroll
            for (int r = 0; r < 4; ++r)
                acc[rt][ci][r] = fmaxf(acc[rt][ci][r] + bv, 0.f);
    }

    int gmin = sbatch[0];
    int gmax = batch[min(n0 + 63, N - 1)];
    for (int gg = gmin; gg <= gmax; ++gg) {
#pragma unroll
        for (int ci = 0; ci < 2; ++ci) {
            float p = 0.f;
#pragma unroll
            for (int rt = 0; rt < 4; ++rt) {
                int lbase = rt * 16 + quad * 4;
#pragma unroll
                for (int r = 0; r < 4; ++r)
                    if (sbatch[lbase + r] == gg) p += acc[rt][ci][r];
            }
            p += __shfl_xor(p, 16, 64);
            p += __shfl_xor(p, 32, 64);
            if (quad == 0)
                atomicAdd(&pooled[gg * HID_C + wv * 32 + ci * 16 + l16], p);
        }
    }
}

// ---------------------------------------------------------------------------
// Head: mean, fc1+relu, fc2, softmax (all fp32). One block per graph.
// ---------------------------------------------------------------------------
__global__ __launch_bounds__(128) void head_kernel(
    const float* __restrict__ pooled, const float* __restrict__ cnts,
    const float* __restrict__ fc1w, const float* __restrict__ fc1b,
    const float* __restrict__ fc2w, const float* __restrict__ fc2b,
    float* __restrict__ out)
{
    __shared__ float sp[HID_C];
    __shared__ float so[HID_C];
    __shared__ float sl[64];
    __shared__ float sred[2];
    int g = blockIdx.x;
    int j = threadIdx.x;

    float inv = 1.f / fmaxf(cnts[g], 1.f);
    sp[j] = pooled[g * HID_C + j] * inv;
    __syncthreads();

    float a = fc1b[j];
    for (int k = 0; k < HID_C; ++k) a = fmaf(sp[k], fc1w[k * HID_C + j], a);
    so[j] = fmaxf(a, 0.f);
    __syncthreads();

    if (j < N_ASSETS_C) {
        float l = fc2b[j];
        for (int k = 0; k < HID_C; ++k) l = fmaf(so[k], fc2w[k * N_ASSETS_C + j], l);
        sl[j] = l;
    }
    __syncthreads();

    if (j == 0) {
        float m = -1e30f;
        for (int q = 0; q < N_ASSETS_C; ++q) m = fmaxf(m, sl[q]);
        sred[0] = m;
    }
    __syncthreads();
    if (j < N_ASSETS_C) sl[j] = expf(sl[j] - sred[0]);
    __syncthreads();
    if (j == 0) {
        float s = 0.f;
        for (int q = 0; q < N_ASSETS_C; ++q) s += sl[q];
        sred[1] = 1.f / s;
    }
    __syncthreads();
    if (j < N_ASSETS_C) out[g * N_ASSETS_C + j] = sl[j] * sred[1];
}

// ---------------------------------------------------------------------------
extern "C" void kernel_launch(void* const* d_in, const int* in_sizes, int n_in,
                              void* d_out, int out_size, void* d_ws, size_t ws_size,
                              hipStream_t stream)
{
    const float* x       = (const float*)d_in[0];
    const int*   ei      = (const int*)d_in[1];
    const int*   batch   = (const int*)d_in[2];
    const float* w1_rel  = (const float*)d_in[3];
    const float* b1      = (const float*)d_in[4];
    const float* w1_root = (const float*)d_in[5];
    const float* w2_rel  = (const float*)d_in[6];
    const float* b2      = (const float*)d_in[7];
    const float* w2_root = (const float*)d_in[8];
    const float* fc1w    = (const float*)d_in[9];
    const float* fc1b    = (const float*)d_in[10];
    const float* fc2w    = (const float*)d_in[11];
    const float* fc2b    = (const float*)d_in[12];
    float* out = (float*)d_out;

    char* ws = (char*)d_ws;
    unsigned*       tmp     = (unsigned*)(ws + 0);              //  6,400,000
    int*            col     = (int*)(ws + 6400000);             //  6,400,000
    int*            row_ptr = (int*)(ws + 12800000);            //    400,016
    int*            bcnt    = (int*)(ws + 13200016);            //        800
    int*            bbase   = (int*)(ws + 13200816);            //        800
    int*            gcur    = (int*)(ws + 13201616);            //        800
    unsigned short* wp1r    = (unsigned short*)(ws + 13202432); //     32,768
    unsigned short* wp1o    = (unsigned short*)(ws + 13235200); //     32,768
    unsigned short* wp2r    = (unsigned short*)(ws + 13267968); //     65,536
    unsigned short* wp2o    = (unsigned short*)(ws + 13333504); //     65,536
    float*          pooled  = (float*)(ws + 13399040);          //     32,768
    float*          cnts    = (float*)(ws + 13431808);          //        256
    unsigned short* xb      = (unsigned short*)(ws + 13432064); // 12,800,000
    unsigned short* agg1b   = (unsigned short*)(ws + 26232064); // 12,800,000
    unsigned short* h1b     = (unsigned short*)(ws + 39032064); // 25,600,000
    unsigned short* agg2b   = (unsigned short*)(ws + 64632064); // 25,600,000

    hipMemsetAsync(pooled, 0, 33024, stream);   // pooled + cnts
    hipMemsetAsync(bcnt, 0, 800, stream);

    // ---- merged preprocessing (cast | pack | count) ----
    preproc_kernel<<<PP_NB, 256, 0, stream>>>(
        x, xb, w1_rel, w1_root, w2_rel, w2_root,
        wp1r, wp1o, wp2r, wp2o, batch, cnts);

    // ---- CSR build (bucketed counting sort, r6-exact) ----
    bucket_hist_kernel<<<(N_EDGES_C + 2047) / 2048, 256, 0, stream>>>(ei, bcnt);
    bucket_scan_kernel<<<1, 256, 0, stream>>>(bcnt, bbase, gcur);
    partition_kernel<<<NBLK_A, 256, 0, stream>>>(ei, gcur, tmp);
    bucket_sort_kernel<<<NB_BKT, 256, 0, stream>>>(tmp, bbase, row_ptr, col);

    const int ggrid = (N_NODES_C + 3) / 4;       // 25000
    const int cgrid = (N_NODES_C + 63) / 64;     // 1563

    // ---- Layer 1 ----
    gather_bf64_kernel<<<ggrid, 256, 0, stream>>>(xb, row_ptr, col, agg1b);
    conv_mfma_kernel<IN_DIM_C, IN_DIM_C><<<cgrid, 256, 0, stream>>>(
        agg1b, xb, wp1r, wp1o, b1, h1b, N_NODES_C);

    // ---- Layer 2 (pool fused into epilogue) ----
    gather_bf128_kernel<<<ggrid, 256, 0, stream>>>(h1b, row_ptr, col, agg2b);
    conv_mfma_pool_kernel<HID_C, HID_C><<<cgrid, 256, 0, stream>>>(
        agg2b, h1b, wp2r, wp2o, b2, batch, pooled, N_NODES_C);

    // ---- Head ----
    head_kernel<<<N_GRAPHS_C, 128, 0, stream>>>(pooled, cnts, fc1w, fc1b, fc2w, fc2b, out);
}